// Round 4
// baseline (1198.341 us; speedup 1.0000x reference)
//
#include <hip/hip_runtime.h>
#include <cstdint>

typedef short s16x8 __attribute__((ext_vector_type(8)));
typedef float f32x4 __attribute__((ext_vector_type(4)));
typedef unsigned short u16;

#define DEV static __device__ __forceinline__

DEV float bf2f(u16 b) {
  union { unsigned u; float f; } v; v.u = ((unsigned)b) << 16; return v.f;
}
DEV u16 f2bf(float f) {
  union { float f; unsigned u; } v; v.f = f;
  unsigned r = 0x7fffu + ((v.u >> 16) & 1u);   // RNE
  return (u16)((v.u + r) >> 16);
}
DEV f32x4 vmax4(f32x4 a, f32x4 b) {
  f32x4 r;
  r[0] = fmaxf(a[0], b[0]); r[1] = fmaxf(a[1], b[1]);
  r[2] = fmaxf(a[2], b[2]); r[3] = fmaxf(a[3], b[3]);
  return r;
}

typedef __attribute__((address_space(3))) void lds_void_t;
typedef const __attribute__((address_space(1))) void glob_void_t;

DEV void async_copy16(const void* g, void* l) {
  __builtin_amdgcn_global_load_lds(
      (glob_void_t*)(uintptr_t)g,
      (lds_void_t*)(uint32_t)(uintptr_t)l,
      16, 0, 0);
}

// ---------------- fp32 -> bf16 convert (vectorized x4) ----------------
__global__ void cvt_f32_bf16(const float* __restrict__ in, u16* __restrict__ out, int n4) {
  int i = blockIdx.x * 256 + threadIdx.x;
  if (i < n4) {
    const float4 v = reinterpret_cast<const float4*>(in)[i];
    ushort4 o;
    o.x = f2bf(v.x); o.y = f2bf(v.y); o.z = f2bf(v.z); o.w = f2bf(v.w);
    reinterpret_cast<ushort4*>(out)[i] = o;
  }
}

// ---------------- NT GEMM: C[m,n] = sum_k A[m,k]*B[n,k] ----------------
template <bool OUT_BF16>
__global__ __launch_bounds__(256, 2)
void gemm_nt(const u16* __restrict__ A, const u16* __restrict__ B,
             void* __restrict__ C, int M, int N, int K) {
  __shared__ u16 As[128 * 32];
  __shared__ u16 Bs[128 * 32];
  const int tid  = threadIdx.x;
  const int lane = tid & 63;
  const int wave = tid >> 6;
  const int wr = wave >> 1, wc = wave & 1;
  const int l15 = lane & 15, quad = lane >> 4;
  const int bm = blockIdx.x, bn = blockIdx.y;

  const int srow   = lane >> 2;
  const int schunk = (lane & 3) ^ ((srow >> 1) & 3);
  const int fsw    = (l15 >> 1) & 3;

  f32x4 acc[4][4];
  const f32x4 zero4 = {0.f, 0.f, 0.f, 0.f};
#pragma unroll
  for (int i = 0; i < 4; ++i)
#pragma unroll
    for (int j = 0; j < 4; ++j) acc[i][j] = zero4;

  const size_t Abase = (size_t)(bm * 128) * K;
  const size_t Bbase = (size_t)(bn * 128) * K;

  for (int kt = 0; kt < K; kt += 32) {
#pragma unroll
    for (int c = 0; c < 2; ++c) {
      const int grp = wave * 2 + c;
      const int row = grp * 16 + srow;
      const u16* gA = A + Abase + (size_t)row * K + kt + schunk * 8;
      const u16* gB = B + Bbase + (size_t)row * K + kt + schunk * 8;
      async_copy16(gA, As + grp * 512 + lane * 8);
      async_copy16(gB, Bs + grp * 512 + lane * 8);
    }
    __syncthreads();

    s16x8 af[4], bf[4];
#pragma unroll
    for (int mi = 0; mi < 4; ++mi) {
      const int row = wr * 64 + mi * 16 + l15;
      af[mi] = *(const s16x8*)(As + row * 32 + (quad ^ fsw) * 8);
    }
#pragma unroll
    for (int ni = 0; ni < 4; ++ni) {
      const int row = wc * 64 + ni * 16 + l15;
      bf[ni] = *(const s16x8*)(Bs + row * 32 + (quad ^ fsw) * 8);
    }
#pragma unroll
    for (int mi = 0; mi < 4; ++mi)
#pragma unroll
      for (int ni = 0; ni < 4; ++ni)
        acc[mi][ni] = __builtin_amdgcn_mfma_f32_16x16x32_bf16(af[mi], bf[ni], acc[mi][ni], 0, 0, 0);
    __syncthreads();
  }

#pragma unroll
  for (int mi = 0; mi < 4; ++mi) {
#pragma unroll
    for (int ni = 0; ni < 4; ++ni) {
      const int gm0 = bm * 128 + wr * 64 + mi * 16 + quad * 4;
      const int gn  = bn * 128 + wc * 64 + ni * 16 + l15;
#pragma unroll
      for (int r = 0; r < 4; ++r) {
        const size_t idx = (size_t)(gm0 + r) * N + gn;
        if (OUT_BF16) ((u16*)C)[idx] = f2bf(acc[mi][ni][r]);
        else          ((float*)C)[idx] = acc[mi][ni][r];
      }
    }
  }
}

// ---------------- RoPE + split + layout change (vectorized x4) ----------------
// Q gets 96^-0.5 * log2(e) folded in: attention softmax runs in exp2 domain.
__global__ void rope_split(const u16* __restrict__ qkv, u16* __restrict__ Q,
                           u16* __restrict__ Kb, u16* __restrict__ Vt) {
  const int tok = blockIdx.x;          // 0..4095
  const int b = tok >> 11, l = tok & 2047;
  const float pos = (float)l;
  const float SF = 1.1902380714238083f;          // sqrt(1 + log(32)/log(4096))
  const float QSCALE = 0.14724444547079517f;     // 96^-0.5 * log2(e)
  const size_t base = (size_t)tok * 9216;
  for (int i = threadIdx.x; i < 768; i += 256) {
    const int g = i * 4;
    const int h = g / 96, d0 = g - h * 96;
    const ushort4 qv4 = *(const ushort4*)(qkv + base + g);
    const ushort4 kv4 = *(const ushort4*)(qkv + base + 3072 + g);
    const ushort4 vv4 = *(const ushort4*)(qkv + base + 6144 + g);
    const int dp0    = (d0 < 48) ? d0 + 48 : d0 - 48;
    const float sgn  = (d0 < 48) ? -1.0f : 1.0f;
    const ushort4 qp4 = *(const ushort4*)(qkv + base + h * 96 + dp0);
    const ushort4 kp4 = *(const ushort4*)(qkv + base + 3072 + h * 96 + dp0);
    const int fi0 = (d0 < 48) ? d0 : d0 - 48;
    const int bh = b * 32 + h;
    ushort4 qo, ko;
    const u16* qvp = (const u16*)&qv4; const u16* kvp = (const u16*)&kv4;
    const u16* qpp = (const u16*)&qp4; const u16* kpp = (const u16*)&kp4;
    const u16* vvp = (const u16*)&vv4;
    u16* qop = (u16*)&qo; u16* kop = (u16*)&ko;
#pragma unroll
    for (int e = 0; e < 4; ++e) {
      const float inv = exp2f(-13.287712379549449f * ((float)(fi0 + e) * (1.0f / 48.0f)));
      const float ang = pos * inv;
      float s, c;
      sincosf(ang, &s, &c);
      c *= SF; s *= SF;
      const float qout = bf2f(qvp[e]) * c + bf2f(qpp[e]) * sgn * s;
      const float kout = bf2f(kvp[e]) * c + bf2f(kpp[e]) * sgn * s;
      qop[e] = f2bf(qout * QSCALE);
      kop[e] = f2bf(kout);
      Vt[((size_t)bh * 96 + d0 + e) * 2048 + l] = vvp[e];
    }
    *(ushort4*)(Q  + ((size_t)bh * 2048 + l) * 96 + d0) = qo;
    *(ushort4*)(Kb + ((size_t)bh * 2048 + l) * 96 + d0) = ko;
  }
}

// ---------------- flash attention (causal), transposed-score form ----------------
// S^T = mfma(K_frag, Q_frag): C-layout col=l15=q, row=quad*4+r=key.
// Each lane's 16 scores belong to ONE q-row -> softmax = local VALU tree + 2 shfls.
// O^T = mfma(V_frag, P_frag): col=l15=q -> alpha scaling is per-lane, no shfl.
// exp2 domain (log2e folded into Q). Batched K loads; V preloaded before softmax.
__global__ __launch_bounds__(256, 3)
void attn(const u16* __restrict__ Q, const u16* __restrict__ Kb,
          const u16* __restrict__ Vt, u16* __restrict__ ctx) {
  const int qb = 31 - blockIdx.x;   // heavy blocks first
  const int bh = blockIdx.y;        // 0..63
  const int tid = threadIdx.x, lane = tid & 63, wave = tid >> 6;
  const int l15 = lane & 15, quad = lane >> 4;
  __shared__ alignas(16) u16 Pl[4][16][72];   // per-wave P^T->A-layout staging

  const size_t hbase = (size_t)bh * 2048 * 96;
  const int q0 = qb * 64 + wave * 16;

  // Q fragment (B operand): lane n=l15 -> q row, k = quad*8+j
  s16x8 qf[3];
#pragma unroll
  for (int c = 0; c < 3; ++c)
    qf[c] = *(const s16x8*)(Q + hbase + (size_t)(q0 + l15) * 96 + c * 32 + quad * 8);

  float m_ = -1e30f, l_ = 0.f;
  f32x4 o[6];
  const f32x4 zero4 = {0.f, 0.f, 0.f, 0.f};
#pragma unroll
  for (int t = 0; t < 6; ++t) o[t] = zero4;

  for (int kb = 0; kb <= qb; ++kb) {
    const int k0 = kb * 64;
    const bool last = (kb == qb);
    const int nsub   = last ? (wave + 1) : 4;        // live 16-key subtiles
    const int nchunk = last ? ((wave >> 1) + 1) : 2; // live PV 32-key chunks
    const int nsw    = nchunk * 2;                   // P subtiles written to LDS

    // ---- batched K fragment loads (A operand: lane m=l15 -> key row) ----
    s16x8 kf[4][3];
#pragma unroll
    for (int sub = 0; sub < 4; ++sub) {
      if (sub < nsub) {
        const size_t kro = hbase + (size_t)(k0 + sub * 16 + l15) * 96 + quad * 8;
        kf[sub][0] = *(const s16x8*)(Kb + kro);
        kf[sub][1] = *(const s16x8*)(Kb + kro + 32);
        kf[sub][2] = *(const s16x8*)(Kb + kro + 64);
      }
    }

    // ---- QK^T (transposed): rows=keys, cols=q ----
    f32x4 s[4];
#pragma unroll
    for (int sub = 0; sub < 4; ++sub) {
      if (sub < nsub) {
        f32x4 t = __builtin_amdgcn_mfma_f32_16x16x32_bf16(kf[sub][0], qf[0], zero4, 0, 0, 0);
        t = __builtin_amdgcn_mfma_f32_16x16x32_bf16(kf[sub][1], qf[1], t, 0, 0, 0);
        t = __builtin_amdgcn_mfma_f32_16x16x32_bf16(kf[sub][2], qf[2], t, 0, 0, 0);
        s[sub] = t;
      } else {
        s[sub] = (f32x4){-1e30f, -1e30f, -1e30f, -1e30f};
      }
    }

    // ---- V fragment preloads (overlap latency with softmax below) ----
    s16x8 vf[2][6];
#pragma unroll
    for (int c = 0; c < 2; ++c) {
      if (c < nchunk) {
#pragma unroll
        for (int t = 0; t < 6; ++t)
          vf[c][t] = *(const s16x8*)(Vt + ((size_t)bh * 96 + t * 16 + l15) * 2048
                                        + k0 + c * 32 + quad * 8);
      }
    }

    // causal mask (diagonal block only): key = k0+sub*16+quad*4+r, q = q0+l15
    if (last) {
      const int qrow = q0 + l15;
#pragma unroll
      for (int sub = 0; sub < 4; ++sub)
#pragma unroll
        for (int r = 0; r < 4; ++r) {
          const int key = k0 + sub * 16 + quad * 4 + r;
          if (key > qrow) s[sub][r] = -1e30f;
        }
    }

    // ---- online softmax: per-lane local tree + 2 shfls ----
    f32x4 vm = vmax4(vmax4(s[0], s[1]), vmax4(s[2], s[3]));
    float mx = fmaxf(fmaxf(vm[0], vm[1]), fmaxf(vm[2], vm[3]));
    mx = fmaxf(mx, __shfl_xor(mx, 16));
    mx = fmaxf(mx, __shfl_xor(mx, 32));
    const float mn = fmaxf(m_, mx);
    const float alpha = exp2f(m_ - mn);
    m_ = mn;
#pragma unroll
    for (int sub = 0; sub < 4; ++sub)
#pragma unroll
      for (int r = 0; r < 4; ++r)
        s[sub][r] = exp2f(s[sub][r] - mn);
    f32x4 vs;
#pragma unroll
    for (int r = 0; r < 4; ++r) vs[r] = (s[0][r] + s[1][r]) + (s[2][r] + s[3][r]);
    float rs = (vs[0] + vs[1]) + (vs[2] + vs[3]);
    rs += __shfl_xor(rs, 16);
    rs += __shfl_xor(rs, 32);
    l_ = l_ * alpha + rs;
#pragma unroll
    for (int t = 0; t < 6; ++t)
#pragma unroll
      for (int r = 0; r < 4; ++r) o[t][r] *= alpha;

    // ---- P^T (C-layout) -> LDS as A/B-layout source: Pl[q][key], packed b64 ----
#pragma unroll
    for (int sub = 0; sub < 4; ++sub) {
      if (sub < nsw) {
        ushort4 pk;
        pk.x = f2bf(s[sub][0]); pk.y = f2bf(s[sub][1]);
        pk.z = f2bf(s[sub][2]); pk.w = f2bf(s[sub][3]);
        *(ushort4*)(&Pl[wave][l15][sub * 16 + quad * 4]) = pk;
      }
    }

    // ---- PV: O^T += mfma(V_frag, P_frag) ----
#pragma unroll
    for (int c = 0; c < 2; ++c) {
      if (c < nchunk) {
        const s16x8 pf = *(const s16x8*)(&Pl[wave][l15][c * 32 + quad * 8]);
#pragma unroll
        for (int t = 0; t < 6; ++t)
          o[t] = __builtin_amdgcn_mfma_f32_16x16x32_bf16(vf[c][t], pf, o[t], 0, 0, 0);
      }
    }
  }

  // ---- write ctx[b, q, h*96 + d]: lane q=q0+l15, d = t*16+quad*4+r (packed 8B) ----
  const int b = bh >> 5, h = bh & 31;
  const float invl = 1.0f / l_;
  const size_t rowbase = ((size_t)(b * 2048 + q0 + l15)) * 3072 + h * 96;
#pragma unroll
  for (int t = 0; t < 6; ++t) {
    ushort4 w;
    w.x = f2bf(o[t][0] * invl); w.y = f2bf(o[t][1] * invl);
    w.z = f2bf(o[t][2] * invl); w.w = f2bf(o[t][3] * invl);
    *(ushort4*)(ctx + rowbase + t * 16 + quad * 4) = w;
  }
}

// ---------------- launch ----------------
extern "C" void kernel_launch(void* const* d_in, const int* in_sizes, int n_in,
                              void* d_out, int out_size, void* d_ws, size_t ws_size,
                              hipStream_t stream) {
  const float* x    = (const float*)d_in[0];   // [2,2048,3072]
  const float* Wqkv = (const float*)d_in[1];   // [9216,3072]
  const float* Wo   = (const float*)d_in[2];   // [3072,3072]
  float* out = (float*)d_out;                  // [2,2048,3072] fp32

  char* ws = (char*)d_ws;
  u16* wq_b  = (u16*)(ws);                  // 56,623,104 B
  u16* wo_b  = (u16*)(ws + 56623104);       // 18,874,368 B
  u16* x_b   = (u16*)(ws + 75497472);       // 25,165,824 B
  u16* qkv_b = (u16*)(ws + 100663296);      // 75,497,472 B
  u16* K_b   = (u16*)(ws + 176160768);      // 25,165,824 B
  u16* Vt_b  = (u16*)(ws + 201326592);      // 25,165,824 B
  u16* Q_b   = x_b;                         // alias: x dead after GEMM1
  u16* ctx_b = qkv_b;                       // alias: qkv dead after rope_split

  cvt_f32_bf16<<<27648, 256, 0, stream>>>(Wqkv, wq_b, 28311552 / 4);
  cvt_f32_bf16<<<9216,  256, 0, stream>>>(Wo,   wo_b,  9437184 / 4);
  cvt_f32_bf16<<<12288, 256, 0, stream>>>(x,    x_b,  12582912 / 4);

  // qkv = x @ Wqkv^T   [4096 x 9216], K=3072
  gemm_nt<true><<<dim3(32, 72), 256, 0, stream>>>(x_b, wq_b, (void*)qkv_b, 4096, 9216, 3072);

  rope_split<<<4096, 256, 0, stream>>>(qkv_b, Q_b, K_b, Vt_b);

  attn<<<dim3(32, 64), 256, 0, stream>>>(Q_b, K_b, Vt_b, ctx_b);

  // out = ctx @ Wo^T   [4096 x 3072], K=3072, fp32 out
  gemm_nt<false><<<dim3(32, 24), 256, 0, stream>>>(ctx_b, wo_b, (void*)out, 4096, 3072, 3072);
}